// Round 14
// baseline (42.748 us; speedup 1.0000x reference)
//
#include <hip/hip_runtime.h>

typedef __attribute__((ext_vector_type(8))) short bf16x8;
typedef __attribute__((ext_vector_type(4))) float f32x4;

constexpr int TN = 8192;   // tokens
constexpr int DN = 4096;   // model dim
constexpr int EN = 64;     // experts

constexpr int NS     = DN / 32;    // 128 K32 slots total
constexpr int KSPLIT = 16;         // k-sixteenth per block
constexpr int SLOTS  = NS / KSPLIT;// 8 K32 slots per block (256 k)
constexpr int RB     = 512;        // rows per block
constexpr int RW     = 64;         // rows per wave (4 halves of 16)

__device__ __forceinline__ unsigned short f2bf(float f) {  // RNE f32->bf16
    unsigned u = __builtin_bit_cast(unsigned, f);
    u += 0x7FFFu + ((u >> 16) & 1u);
    return (unsigned short)(u >> 16);
}
__device__ __forceinline__ float bf2f(unsigned short h) {
    unsigned u = ((unsigned)h) << 16;
    return __builtin_bit_cast(float, u);
}
// RNE hi/lo bf16 split of an f32 pair, packed (f1<<16|f0); ~14 VALU/pair.
__device__ __forceinline__ void split_pair(float f0, float f1,
                                           unsigned& hi, unsigned& lo) {
    unsigned u0 = __builtin_bit_cast(unsigned, f0);
    unsigned u1 = __builtin_bit_cast(unsigned, f1);
    unsigned r0 = u0 + 0x7FFFu + ((u0 >> 16) & 1u);
    unsigned r1 = u1 + 0x7FFFu + ((u1 >> 16) & 1u);
    hi = __builtin_amdgcn_perm(r1, r0, 0x07060302u);  // {r1.hi16, r0.hi16}
    float h0 = __builtin_bit_cast(float, r0 & 0xFFFF0000u);
    float h1 = __builtin_bit_cast(float, r1 & 0xFFFF0000u);
    unsigned v0 = __builtin_bit_cast(unsigned, f0 - h0);
    unsigned v1 = __builtin_bit_cast(unsigned, f1 - h1);
    unsigned s0 = v0 + 0x7FFFu + ((v0 >> 16) & 1u);
    unsigned s1 = v1 + 0x7FFFu + ((v1 >> 16) & 1u);
    lo = __builtin_amdgcn_perm(s1, s0, 0x07060302u);
}

// Kernel 0: split wg into hi/lo bf16 planes in MFMA-fragment order:
// BF[p][s][et][lane*8+j] = plane_p( wg[et*16+(lane&15)][s*32+(lane>>4)*8+j] ).
__global__ __launch_bounds__(256)
void wg_frag_kernel(const float* __restrict__ wg, unsigned short* __restrict__ BF) {
    const int gid = blockIdx.x * 256 + threadIdx.x;  // 65536 items
    const int l  = gid & 63;
    const int et = (gid >> 6) & 3;
    const int s  = (gid >> 8) & (NS - 1);
    const int p  = gid >> 15;
    const int e  = et * 16 + (l & 15);
    const int k  = s * 32 + (l >> 4) * 8;

    const float* src = wg + (size_t)e * DN + k;
    float4 v0 = *reinterpret_cast<const float4*>(src);
    float4 v1 = *reinterpret_cast<const float4*>(src + 4);
    float f[8] = {v0.x, v0.y, v0.z, v0.w, v1.x, v1.y, v1.z, v1.w};
    unsigned short o[8];
#pragma unroll
    for (int j = 0; j < 8; ++j) {
        unsigned short h = f2bf(f[j]);
        o[j] = p ? f2bf(f[j] - bf2f(h)) : h;
    }
    unsigned short* dst = BF + (((size_t)p * NS + s) * 4 + et) * 512 + (size_t)l * 8;
    *reinterpret_cast<ushort4*>(dst)     = make_ushort4(o[0], o[1], o[2], o[3]);
    *reinterpret_cast<ushort4*>(dst + 4) = make_ushort4(o[4], o[5], o[6], o[7]);
}

// Kernel 1: B-in-LDS split-bf16 MFMA GEMM, K-split partials.
// Grid = 16 row-tiles x 16 ksplits = 256 blocks (1/CU), 512 thr = 8 waves.
// Block owns 8 K32 slots (256 k); its B (hi+lo, 64KB) is staged into LDS
// ONCE and fragments re-read via ds_read_b128 -- removes 2/3 of the
// per-CU global-path bytes (the measured ~20 B/cyc/CU delivery limit).
// Wave w owns rows r0+w*64..+63 (4 halves of 16) and iterates all 8 slots
// independently (no in-loop barriers; LDS is read-only after stage).
// A gathered per-lane from x, hi/lo split in-register; A depth-2 ping-pong.
__global__ __launch_bounds__(512, 2)
void gate_gemm_kernel(const float* __restrict__ x,
                      const unsigned short* __restrict__ BF,
                      float* __restrict__ part) {
    __shared__ uint4 LB[SLOTS * 512];   // 64 KB: [slot][plane(2)][et*64+lane]

    const int tid  = threadIdx.x;
    const int lane = tid & 63;
    const int w    = tid >> 6;          // wave 0..7
    const int rt   = blockIdx.x >> 4;
    const int ks   = blockIdx.x & 15;   // bid&7 = XCD (round-robin) -> 2 B-16ths/XCD L2
    const int r0   = rt * RB;

    const int fr = lane & 15;           // fragment row (A) / expert col (B)
    const int g  = lane >> 4;           // k-group within K=32
    const int fko = g * 8;

    // stage B: 4096 uint4 (64KB), 8 iters x 512 threads, fully coalesced
    {
        const uint4* gh = reinterpret_cast<const uint4*>(BF);
        const uint4* gl = gh + 32768;   // lo plane at +512KB
#pragma unroll
        for (int i = 0; i < 8; ++i) {
            int e = tid + i * 512;
            int slot = e >> 9, plane = (e >> 8) & 1, off = e & 255;
            int gidx = (ks * SLOTS + slot) * 256 + off;
            LB[e] = plane ? gl[gidx] : gh[gidx];
        }
    }
    __syncthreads();                    // only barrier; LDS read-only after

    const float* xa = x + (size_t)(r0 + w * RW + fr) * DN + fko;

    f32x4 acc[4][4] = {};               // [row-half][expert-tile]
    float4 XA[2][4][2];                 // depth-2 A fp32 [set][rh][2x float4]

    auto loadA = [&](int set, int t) {
        const float* p = xa + (size_t)(ks * SLOTS + t) * 32;
#pragma unroll
        for (int rh = 0; rh < 4; ++rh) {
            const float* pr = p + (size_t)rh * 16 * DN;
            XA[set][rh][0] = *reinterpret_cast<const float4*>(pr);
            XA[set][rh][1] = *reinterpret_cast<const float4*>(pr + 4);
        }
    };
    auto compute = [&](int set, int t) {
        bf16x8 bh[4], bl[4];
#pragma unroll
        for (int et = 0; et < 4; ++et) {
            bh[et] = __builtin_bit_cast(bf16x8, LB[t * 512 + et * 64 + lane]);
            bl[et] = __builtin_bit_cast(bf16x8, LB[t * 512 + 256 + et * 64 + lane]);
        }
        bf16x8 ah[4], al[4];
#pragma unroll
        for (int rh = 0; rh < 4; ++rh) {
            float f[8] = {XA[set][rh][0].x, XA[set][rh][0].y,
                          XA[set][rh][0].z, XA[set][rh][0].w,
                          XA[set][rh][1].x, XA[set][rh][1].y,
                          XA[set][rh][1].z, XA[set][rh][1].w};
            unsigned uh[4], ul[4];
#pragma unroll
            for (int q = 0; q < 4; ++q)
                split_pair(f[2 * q], f[2 * q + 1], uh[q], ul[q]);
            uint4 vh = make_uint4(uh[0], uh[1], uh[2], uh[3]);
            uint4 vl = make_uint4(ul[0], ul[1], ul[2], ul[3]);
            ah[rh] = __builtin_bit_cast(bf16x8, vh);
            al[rh] = __builtin_bit_cast(bf16x8, vl);
        }
        // product-outer order: 16 independent acc chains between reuses
#pragma unroll
        for (int et = 0; et < 4; ++et)
#pragma unroll
            for (int rh = 0; rh < 4; ++rh)
                acc[rh][et] = __builtin_amdgcn_mfma_f32_16x16x32_bf16(ah[rh], bh[et], acc[rh][et], 0, 0, 0);
#pragma unroll
        for (int et = 0; et < 4; ++et)
#pragma unroll
            for (int rh = 0; rh < 4; ++rh)
                acc[rh][et] = __builtin_amdgcn_mfma_f32_16x16x32_bf16(al[rh], bh[et], acc[rh][et], 0, 0, 0);
#pragma unroll
        for (int et = 0; et < 4; ++et)
#pragma unroll
            for (int rh = 0; rh < 4; ++rh)
                acc[rh][et] = __builtin_amdgcn_mfma_f32_16x16x32_bf16(ah[rh], bl[et], acc[rh][et], 0, 0, 0);
#pragma unroll
        for (int et = 0; et < 4; ++et)
#pragma unroll
            for (int rh = 0; rh < 4; ++rh)
                acc[rh][et] = __builtin_amdgcn_mfma_f32_16x16x32_bf16(al[rh], bl[et], acc[rh][et], 0, 0, 0);
    };

    loadA(0, 0);
    loadA(1, 1);
#pragma unroll
    for (int t = 0; t < SLOTS; ++t) {   // full unroll: set indices static
        compute(t & 1, t);
        if (t + 2 < SLOTS) loadA(t & 1, t + 2);
        asm volatile("" ::: "memory");  // pin per-phase issue order
    }

    // partial store straight from registers (no cross-wave reduce needed:
    // each wave owns distinct rows). C/D: col=lane&15, row=(lane>>4)*4+reg.
    float* dst = part + ((size_t)ks * TN + r0 + w * RW) * EN;
#pragma unroll
    for (int rh = 0; rh < 4; ++rh)
#pragma unroll
        for (int et = 0; et < 4; ++et)
#pragma unroll
            for (int r = 0; r < 4; ++r)
                dst[(size_t)(rh * 16 + g * 4 + r) * EN + et * 16 + fr] = acc[rh][et][r];
}

// Kernel 2: sum 16 partials, top-1 softmax. 16 threads/row (4 experts each),
// shuffle-reduce. out[0..TN) = argmax idx (float), out[TN..2TN) = max gate.
__global__ __launch_bounds__(256)
void top1_softmax_kernel(const float* __restrict__ part, float* __restrict__ out) {
    const int gid = blockIdx.x * blockDim.x + threadIdx.x;
    const int row = gid >> 4;
    const int eg  = gid & 15;
    if (row >= TN) return;

    float v[4] = {};
#pragma unroll
    for (int h = 0; h < KSPLIT; ++h) {
        float4 t = *reinterpret_cast<const float4*>(
            &part[((size_t)h * TN + row) * EN + eg * 4]);
        v[0] += t.x; v[1] += t.y; v[2] += t.z; v[3] += t.w;
    }
    float m = v[0];
    int idx = eg * 4;
#pragma unroll
    for (int j = 1; j < 4; ++j)
        if (v[j] > m) { m = v[j]; idx = eg * 4 + j; }  // strict >: first occurrence
#pragma unroll
    for (int d = 1; d < 16; d <<= 1) {
        float om = __shfl_xor(m, d);
        int   oi = __shfl_xor(idx, d);
        if (om > m || (om == m && oi < idx)) { m = om; idx = oi; }
    }
    float s = 0.0f;
#pragma unroll
    for (int j = 0; j < 4; ++j) s += __expf(v[j] - m);
#pragma unroll
    for (int d = 1; d < 16; d <<= 1) s += __shfl_xor(s, d);
    if (eg == 0) {
        out[row]      = (float)idx;     // argmax index
        out[TN + row] = 1.0f / s;       // max gate = 1/sum(exp(l-lmax))
    }
}

extern "C" void kernel_launch(void* const* d_in, const int* in_sizes, int n_in,
                              void* d_out, int out_size, void* d_ws, size_t ws_size,
                              hipStream_t stream) {
    const float* x  = (const float*)d_in[0];
    const float* wg = (const float*)d_in[1];
    float* out = (float*)d_out;

    constexpr size_t BF_BYTES = (size_t)2 * NS * 4 * 512 * 2;  // 1 MB
    unsigned short* BF = (unsigned short*)d_ws;
    float* part = (float*)((char*)d_ws + BF_BYTES);            // 32 MB partials

    wg_frag_kernel<<<dim3(256), dim3(256), 0, stream>>>(wg, BF);
    gate_gemm_kernel<<<dim3((TN / RB) * KSPLIT), dim3(512), 0, stream>>>(x, BF, part);
    top1_softmax_kernel<<<dim3(TN * 16 / 256), dim3(256), 0, stream>>>(part, out);
}